// Round 10
// baseline (428.332 us; speedup 1.0000x reference)
//
#include <hip/hip_runtime.h>
#include <hip/hip_bf16.h>
#include <math.h>

// Shapes
#define B_  4
#define E_  768
#define NH_ 12
#define DH_ 64
#define LL_ 2
#define DFF_ 3072
#define OUT_ 1000
#define S_  197
#define ROWS_ 788          // B_*S_
#define QH_P 12608         // 197*64 per-head q/v pitch

typedef __bf16 bf16x8_t __attribute__((ext_vector_type(8)));
typedef float f32x4_t __attribute__((ext_vector_type(4)));

__device__ __forceinline__ float gelu_f(float x) {
    float x3 = x * x * x;
    return 0.5f * x * (1.0f + tanhf(0.7978845608028654f * (x + 0.044715f * x3)));
}
__device__ __forceinline__ float bf16bits_to_f(uint u) { return __uint_as_float(u << 16); }
__device__ __forceinline__ ushort f_to_bf16bits(float f) {
    __hip_bfloat16 b = __float2bfloat16(f);
    return *(ushort*)&b;
}

// ---------------- merged prologue prep: im2col + all weight transposes + conv cvt ----------------
#define WT_CONV   0
#define WT_LBASE  589824
#define WT_LSTRIDE 7077888
#define WT_QKV    0
#define WT_PROJ   1769472
#define WT_FC1    2359296
#define WT_FC2    4718592
// grid: 2352 im2col blocks + 13824 transpose tiles + 2304 conv-cvt blocks = 18480
__global__ __launch_bounds__(256) void prep_all_kernel(const float* __restrict__ x,
                                                       __hip_bfloat16* __restrict__ aim,
                                                       const float* __restrict__ attn_w,
                                                       const float* __restrict__ proj_w,
                                                       const float* __restrict__ fc1_w,
                                                       const float* __restrict__ fc2_w,
                                                       const float* __restrict__ conv_w,
                                                       __hip_bfloat16* __restrict__ wt) {
    int bid = blockIdx.x;
    if (bid < 2352) {                       // im2col
        int id = bid * 256 + threadIdx.x;
        int row = id / 768, k = id - row * 768;
        int b = row / 196, pr = row - b * 196;
        int hp = pr / 14, wp = pr - hp * 14;
        int c = k >> 8, rem = k & 255, p = rem >> 4, q = rem & 15;
        aim[id] = __float2bfloat16(x[(((size_t)(b * 3 + c) * 224) + hp * 16 + p) * 224 + wp * 16 + q]);
        return;
    }
    int id = bid - 2352;
    if (id >= 13824) {                      // conv cvt (already [N,K])
        int off = (id - 13824) * 256 + threadIdx.x;
        wt[WT_CONV + off] = __float2bfloat16(conv_w[off]);
        return;
    }
    int l = id / 6912, r = id - l * 6912;
    const float* src;
    __hip_bfloat16* dst;
    int K, N, tile;
    size_t lbase = WT_LBASE + (size_t)l * WT_LSTRIDE;
    if (r < 1728)      { src = attn_w + (size_t)l * E_ * 3 * E_; dst = wt + lbase + WT_QKV;  K = E_;   N = 3 * E_; tile = r; }
    else if (r < 2304) { src = proj_w + (size_t)l * E_ * E_;     dst = wt + lbase + WT_PROJ; K = E_;   N = E_;     tile = r - 1728; }
    else if (r < 4608) { src = fc1_w + (size_t)l * E_ * DFF_;    dst = wt + lbase + WT_FC1;  K = E_;   N = DFF_;   tile = r - 2304; }
    else               { src = fc2_w + (size_t)l * DFF_ * E_;    dst = wt + lbase + WT_FC2;  K = DFF_; N = E_;     tile = r - 4608; }
    int ntn = N / 32;
    int kb = (tile / ntn) * 32, nb = (tile % ntn) * 32;
    __shared__ __hip_bfloat16 t[32][33];
    int tx = threadIdx.x & 31, ty = threadIdx.x >> 5;
#pragma unroll
    for (int rr = 0; rr < 32; rr += 8)
        t[ty + rr][tx] = __float2bfloat16(src[(size_t)(kb + ty + rr) * N + nb + tx]);
    __syncthreads();
#pragma unroll
    for (int rr = 0; rr < 32; rr += 8)
        dst[(size_t)(nb + ty + rr) * K + kb + tx] = t[tx][ty + rr];
}

// ---------------- MFMA GEMM: LDS dbuf, 1 barrier/iter, prefetch depth 2, split-K ----------------
#define BK 64
#define AP 72
__global__ __launch_bounds__(256) void gemm_mfma_kernel(const __hip_bfloat16* __restrict__ A,
                                                        const __hip_bfloat16* __restrict__ WT,
                                                        const float* __restrict__ bias,
                                                        const float* __restrict__ res,
                                                        float* __restrict__ Cf,
                                                        __hip_bfloat16* __restrict__ Cb,
                                                        float* __restrict__ part0,
                                                        float* __restrict__ part1,
                                                        int M, int N, int K, int act, int KS) {
    __shared__ __align__(16) ushort Asb[2][64 * AP];
    __shared__ __align__(16) ushort Bsb[2][64 * AP];
    const int tid = threadIdx.x;
    const int wave = tid >> 6, lane = tid & 63;
    const int quad = lane >> 4, l15 = lane & 15;
    const int wm = wave >> 1, wn = wave & 1;
    const int m0 = blockIdx.y * 64, n0 = blockIdx.x * 64;

    const int Kc   = K / KS;
    const int kbeg = blockIdx.z * Kc;
    const int n_it = Kc / BK;

    f32x4_t acc[2][2] = {};

    const int c0r = tid >> 3,         c0o = (tid & 7) * 8;
    const int c1r = (tid + 256) >> 3, c1o = c0o;

    uint4 pa0, pa1, pb0, pb1;
    auto load_tile = [&](int kk) {
        pa0 = make_uint4(0, 0, 0, 0);
        pa1 = pa0;
        int gm = m0 + c0r;
        if (gm < M) pa0 = *(const uint4*)&A[(size_t)gm * K + kk + c0o];
        gm = m0 + c1r;
        if (gm < M) pa1 = *(const uint4*)&A[(size_t)gm * K + kk + c1o];
        pb0 = *(const uint4*)&WT[(size_t)(n0 + c0r) * K + kk + c0o];
        pb1 = *(const uint4*)&WT[(size_t)(n0 + c1r) * K + kk + c1o];
    };
    auto store_tile = [&](int buf) {
        *(uint4*)&Asb[buf][c0r * AP + c0o] = pa0;
        *(uint4*)&Asb[buf][c1r * AP + c1o] = pa1;
        *(uint4*)&Bsb[buf][c0r * AP + c0o] = pb0;
        *(uint4*)&Bsb[buf][c1r * AP + c1o] = pb1;
    };

    load_tile(kbeg);
    store_tile(0);
    if (n_it > 1) load_tile(kbeg + BK);
    __syncthreads();

    for (int it = 0; it < n_it; ++it) {
        const int cur = it & 1, nxt = cur ^ 1;
        if (it + 1 < n_it) {
            store_tile(nxt);
            if (it + 2 < n_it) load_tile(kbeg + (it + 2) * BK);
        }
        const ushort* As = Asb[cur];
        const ushort* Bs = Bsb[cur];
#pragma unroll
        for (int ks = 0; ks < BK; ks += 32) {
            bf16x8_t a0 = *(const bf16x8_t*)&As[(32 * wm + l15) * AP + ks + 8 * quad];
            bf16x8_t a1 = *(const bf16x8_t*)&As[(32 * wm + 16 + l15) * AP + ks + 8 * quad];
            bf16x8_t b0 = *(const bf16x8_t*)&Bs[(32 * wn + l15) * AP + ks + 8 * quad];
            bf16x8_t b1 = *(const bf16x8_t*)&Bs[(32 * wn + 16 + l15) * AP + ks + 8 * quad];
            acc[0][0] = __builtin_amdgcn_mfma_f32_16x16x32_bf16(a0, b0, acc[0][0], 0, 0, 0);
            acc[0][1] = __builtin_amdgcn_mfma_f32_16x16x32_bf16(a0, b1, acc[0][1], 0, 0, 0);
            acc[1][0] = __builtin_amdgcn_mfma_f32_16x16x32_bf16(a1, b0, acc[1][0], 0, 0, 0);
            acc[1][1] = __builtin_amdgcn_mfma_f32_16x16x32_bf16(a1, b1, acc[1][1], 0, 0, 0);
        }
        __syncthreads();
    }

    if (part0) {
        float* P = blockIdx.z ? part1 : part0;
#pragma unroll
        for (int mi = 0; mi < 2; ++mi)
#pragma unroll
            for (int ni = 0; ni < 2; ++ni) {
                int gn = n0 + 32 * wn + 16 * ni + l15;
#pragma unroll
                for (int r = 0; r < 4; ++r) {
                    int gm = m0 + 32 * wm + 16 * mi + quad * 4 + r;
                    if (gm < M) P[(size_t)gm * N + gn] = acc[mi][ni][r];
                }
            }
        return;
    }

#pragma unroll
    for (int mi = 0; mi < 2; ++mi)
#pragma unroll
        for (int ni = 0; ni < 2; ++ni) {
            int gn = n0 + 32 * wn + 16 * ni + l15;
#pragma unroll
            for (int r = 0; r < 4; ++r) {
                int gm = m0 + 32 * wm + 16 * mi + quad * 4 + r;
                if (gm < M) {
                    float v = acc[mi][ni][r] + bias[gn];
                    if (act == 1) v = gelu_f(v);
                    if (res) v += res[(size_t)gm * N + gn];
                    if (Cf) Cf[(size_t)gm * N + gn] = v;
                    else    Cb[(size_t)gm * N + gn] = __float2bfloat16(v);
                }
            }
        }
}

// ---------------- split-K(2) reduce (fp32 out) ----------------
__global__ __launch_bounds__(256) void splitk_reduce_kernel(const float* __restrict__ p0,
                                                            const float* __restrict__ p1,
                                                            const float* __restrict__ bias,
                                                            const float* __restrict__ res,
                                                            float* __restrict__ Cf,
                                                            int M, int N) {
    int i = blockIdx.x * 256 + threadIdx.x;
    if (i >= M * N) return;
    int n = i % N;
    float v = bias[n] + p0[i] + p1[i];
    if (res) v += res[i];
    Cf[i] = v;
}

// ---------------- embed + cls + LN1(l=0) fused ----------------
__global__ __launch_bounds__(256) void embed_ln_kernel(const float* __restrict__ tmp,
                                                       const float* __restrict__ pe,
                                                       const float* __restrict__ ct,
                                                       const float* __restrict__ lw,
                                                       const float* __restrict__ lb,
                                                       float* __restrict__ h,
                                                       __hip_bfloat16* __restrict__ y) {
    int row = blockIdx.x, tid = threadIdx.x;
    int b = row / S_, s = row - b * S_;
    float v[3];
#pragma unroll
    for (int c = 0; c < 3; ++c) {
        int e = tid + c * 256;
        float t;
        if (s == 0) t = ct[e];
        else {
            int pr = s - 1;
            t = tmp[(size_t)(b * 196 + pr) * E_ + e] + pe[(size_t)pr * E_ + e];
        }
        h[(size_t)row * E_ + e] = t;
        v[c] = t;
    }
    float sm  = v[0] + v[1] + v[2];
    float sq = v[0] * v[0] + v[1] * v[1] + v[2] * v[2];
#pragma unroll
    for (int m = 1; m < 64; m <<= 1) {
        sm += __shfl_xor(sm, m, 64);
        sq += __shfl_xor(sq, m, 64);
    }
    __shared__ float ss[4], sqs[4];
    int wave = tid >> 6, lane = tid & 63;
    if (lane == 0) { ss[wave] = sm; sqs[wave] = sq; }
    __syncthreads();
    sm = ss[0] + ss[1] + ss[2] + ss[3];
    sq = sqs[0] + sqs[1] + sqs[2] + sqs[3];
    float mu   = sm * (1.0f / 768.0f);
    float var  = sq * (1.0f / 768.0f) - mu * mu;
    float rstd = rsqrtf(var + 1e-5f);
    __hip_bfloat16* yr = y + (size_t)row * E_;
#pragma unroll
    for (int c = 0; c < 3; ++c) {
        int e = tid + c * 256;
        yr[e] = __float2bfloat16((v[c] - mu) * rstd * lw[e] + lb[e]);
    }
}

// ---------------- LayerNorm (fp32 in, bf16 out) ----------------
__global__ __launch_bounds__(256) void layernorm_kernel(const float* __restrict__ x,
                                                        const float* __restrict__ w,
                                                        const float* __restrict__ b,
                                                        __hip_bfloat16* __restrict__ y) {
    int row = blockIdx.x;
    const float* xr = x + (size_t)row * E_;
    int tid = threadIdx.x;
    float v0 = xr[tid], v1 = xr[tid + 256], v2 = xr[tid + 512];
    float s  = v0 + v1 + v2;
    float sq = v0 * v0 + v1 * v1 + v2 * v2;
#pragma unroll
    for (int m = 1; m < 64; m <<= 1) {
        s  += __shfl_xor(s, m, 64);
        sq += __shfl_xor(sq, m, 64);
    }
    __shared__ float ss[4], sqs[4];
    int wave = tid >> 6, lane = tid & 63;
    if (lane == 0) { ss[wave] = s; sqs[wave] = sq; }
    __syncthreads();
    s  = ss[0] + ss[1] + ss[2] + ss[3];
    sq = sqs[0] + sqs[1] + sqs[2] + sqs[3];
    float mu   = s * (1.0f / 768.0f);
    float var  = sq * (1.0f / 768.0f) - mu * mu;
    float rstd = rsqrtf(var + 1e-5f);
    __hip_bfloat16* yr = y + (size_t)row * E_;
    yr[tid]       = __float2bfloat16((v0 - mu) * rstd * w[tid]       + b[tid]);
    yr[tid + 256] = __float2bfloat16((v1 - mu) * rstd * w[tid + 256] + b[tid + 256]);
    yr[tid + 512] = __float2bfloat16((v2 - mu) * rstd * w[tid + 512] + b[tid + 512]);
}

// ---------------- attention prep (absorbs QKV split-K reduce + bias) ----------------
// z=0/1: K j-chunks -> ktg bf16 [head][d*256+j] + ksg; z=2: V -> vg bf16 [head][j*64+d];
// z=3: Q -> qg bf16 [head][i*64+d] (relu) + qsg row sums.
#define KT_PP 256
#define PJL 100
__global__ __launch_bounds__(256) void attn_prep_kernel(const float* __restrict__ p0,
                                                        const float* __restrict__ p1,
                                                        const float* __restrict__ ab,
                                                        ushort* __restrict__ ktg,
                                                        float* __restrict__ ksg,
                                                        ushort* __restrict__ qg,
                                                        ushort* __restrict__ vg,
                                                        float* __restrict__ qsg) {
    const int tid = threadIdx.x;
    const int lane = tid & 63;
    const int hh = blockIdx.x, bb = blockIdx.y, zc = blockIdx.z;
    const int head = bb * NH_ + hh;

    if (zc <= 1) {                      // K chunk -> kT transpose + ks
        __shared__ float kT[64][PJL + 1];
        const int j0 = zc * PJL;
        float* ksrow = ksg + (size_t)head * KT_PP;
        const float kb = 0.f;
        for (int c = 0; c < 25; ++c) {
            int idx = c * 256 + tid;
            int jj = idx >> 6, d = idx & 63;
            int j = j0 + jj;
            float val = 0.f;
            if (j < S_) {
                size_t g = ((size_t)(bb * S_ + j)) * (3 * E_) + E_ + hh * DH_ + d;
                val = fmaxf(p0[g] + p1[g] + ab[E_ + hh * DH_ + d] + kb, 0.f);
            }
            kT[d][jj] = val;
            float s = val;
#pragma unroll
            for (int m = 1; m < 64; m <<= 1) s += __shfl_xor(s, m, 64);
            if (j < S_ && lane == 0) ksrow[j] = s;
        }
        if (zc == 1) {
            int jp = PJL + tid;
            if (jp >= S_ && jp < KT_PP) ksrow[jp] = 0.f;
        }
        __syncthreads();
        ushort* orow = ktg + (size_t)head * 64 * KT_PP + j0;
        for (int idx = tid; idx < 64 * PJL; idx += 256) {
            int d = idx / PJL, jj = idx - d * PJL;
            orow[(size_t)d * KT_PP + jj] = f_to_bf16bits(kT[d][jj]);
        }
    } else if (zc == 2) {               // V elementwise
        for (int c = 0; c < 50; ++c) {
            int idx = c * 256 + tid;
            int j = idx >> 6, d = idx & 63;
            if (j < S_) {
                size_t g = ((size_t)(bb * S_ + j)) * (3 * E_) + 2 * E_ + hh * DH_ + d;
                vg[(size_t)head * QH_P + idx] = f_to_bf16bits(p0[g] + p1[g] + ab[2 * E_ + hh * DH_ + d]);
            }
        }
    } else {                            // Q: relu + row sums
        const int wv = tid >> 6;
        for (int c = 0; c < 50; ++c) {
            int i = c * 4 + wv;
            float val = 0.f;
            if (i < S_) {
                size_t g = ((size_t)(bb * S_ + i)) * (3 * E_) + hh * DH_ + lane;
                val = fmaxf(p0[g] + p1[g] + ab[hh * DH_ + lane], 0.f);
                qg[(size_t)head * QH_P + i * 64 + lane] = f_to_bf16bits(val);
            }
            float s = val;
#pragma unroll
            for (int m = 1; m < 64; m <<= 1) s += __shfl_xor(s, m, 64);
            if (i < S_ && lane == 0) qsg[(size_t)head * 200 + i] = s;
        }
    }
}

// ---------------- Tversky attention: kT bf16 LDS, j-quad lanes, RW=4, no-max softmax ----------------
// score(i,j) = (qs+ks-l1)/(qs+ks+2eps) in [~0,1]  [exact for a=b=0.5,g=1]
#define RW 4
#define CHUNK (4 * RW)     // 16 rows per block
__global__ __launch_bounds__(256) void tversky_attn_kernel(const ushort* __restrict__ qg,
                                                           const ushort* __restrict__ ktg,
                                                           const float* __restrict__ ksg,
                                                           const ushort* __restrict__ vg,
                                                           const float* __restrict__ qsg,
                                                           __hip_bfloat16* __restrict__ o) {
    __shared__ __align__(16) ushort kT[64 * KT_PP];      // 32768 B
    __shared__ __align__(16) float ks_l[KT_PP];          // 1024 B
    __shared__ __align__(16) float q_lds[4][RW][64];     // 4096 B
    __shared__ __align__(16) ushort p_lds[4][RW][200];   // 6400 B

    const int tid  = threadIdx.x;
    const int wave = tid >> 6;
    const int lane = tid & 63;
    const int ch = blockIdx.x, hh = blockIdx.y, bb = blockIdx.z;
    const int head = bb * NH_ + hh;

    // stage kT + ks (all threads, before any divergence)
    {
        const uint4* src = (const uint4*)(ktg + (size_t)head * 64 * KT_PP);
        uint4* dst = (uint4*)kT;
#pragma unroll
        for (int c = 0; c < 8; ++c) dst[c * 256 + tid] = src[c * 256 + tid];
        ks_l[tid] = ksg[(size_t)head * KT_PP + tid];
    }
    __syncthreads();

    const int i0 = ch * CHUNK + wave * RW;
    if (i0 >= S_) return;   // after last barrier: safe

    float qs[RW];
#pragma unroll
    for (int r = 0; r < RW; ++r) {
        int i = i0 + r;
        float qp = 0.f, qsv = 0.f;
        if (i < S_) {
            qp  = bf16bits_to_f((uint)qg[(size_t)head * QH_P + i * 64 + lane]);
            qsv = qsg[(size_t)head * 200 + i];
        }
        qs[r] = qsv;
        q_lds[wave][r][lane] = qp;
    }

    // lane covers j-quad {4l..4l+3}; valid j <= 196
    const bool c0v = (lane <= 49);
    const bool cv  = (lane <= 48);

    float l[4][RW] = {};
#pragma unroll 4
    for (int d4 = 0; d4 < 16; ++d4) {
        float4 qv[RW];
#pragma unroll
        for (int r = 0; r < RW; ++r) qv[r] = *(const float4*)&q_lds[wave][r][d4 * 4];
#pragma unroll
        for (int dd = 0; dd < 4; ++dd) {
            int d = d4 * 4 + dd;
            uint2 kp = *(const uint2*)&kT[d * KT_PP + 4 * lane];
            float k0 = bf16bits_to_f(kp.x & 0xffffu);
            float k1 = __uint_as_float(kp.x & 0xffff0000u);
            float k2 = bf16bits_to_f(kp.y & 0xffffu);
            float k3 = __uint_as_float(kp.y & 0xffff0000u);
#pragma unroll
            for (int r = 0; r < RW; ++r) {
                float q = (dd == 0) ? qv[r].x : (dd == 1) ? qv[r].y : (dd == 2) ? qv[r].z : qv[r].w;
                l[0][r] += fabsf(q - k0);
                l[1][r] += fabsf(q - k1);
                l[2][r] += fabsf(q - k2);
                l[3][r] += fabsf(q - k3);
            }
        }
    }

    float4 ks4 = *(const float4*)&ks_l[4 * lane];

    // softmax WITHOUT max-subtraction (scores bounded in [~0,1]); invalid j -> e=0
#pragma unroll
    for (int r = 0; r < RW; ++r) {
        float s0 = qs[r] + ks4.x, s1 = qs[r] + ks4.y;
        float s2 = qs[r] + ks4.z, s3 = qs[r] + ks4.w;
        float e0 = c0v ? expf((s0 - l[0][r]) / (s0 + 2e-8f)) : 0.f;
        float e1 = cv  ? expf((s1 - l[1][r]) / (s1 + 2e-8f)) : 0.f;
        float e2 = cv  ? expf((s2 - l[2][r]) / (s2 + 2e-8f)) : 0.f;
        float e3 = cv  ? expf((s3 - l[3][r]) / (s3 + 2e-8f)) : 0.f;
        float sum = e0 + e1 + e2 + e3;
#pragma unroll
        for (int m = 1; m < 64; m <<= 1) sum += __shfl_xor(sum, m, 64);
        float inv = 1.f / sum;
        if (lane <= 49) {        // lanes 0..49 x 4 = exactly p[0..199]
            uint lo = (uint)f_to_bf16bits(e0 * inv) | ((uint)f_to_bf16bits(e1 * inv) << 16);
            uint hi = (uint)f_to_bf16bits(e2 * inv) | ((uint)f_to_bf16bits(e3 * inv) << 16);
            uint2 w2; w2.x = lo; w2.y = hi;
            *(uint2*)&p_lds[wave][r][4 * lane] = w2;
        }
    }
    // p_lds written & read by same wave only: no barrier needed

    const ushort* vb = vg + (size_t)head * QH_P + lane;
    float acc[RW] = {};
#pragma unroll 4
    for (int j4 = 0; j4 < 196; j4 += 4) {
        float v0 = bf16bits_to_f((uint)vb[(j4 + 0) * 64]);
        float v1 = bf16bits_to_f((uint)vb[(j4 + 1) * 64]);
        float v2 = bf16bits_to_f((uint)vb[(j4 + 2) * 64]);
        float v3 = bf16bits_to_f((uint)vb[(j4 + 3) * 64]);
#pragma unroll
        for (int r = 0; r < RW; ++r) {
            uint2 pp = *(const uint2*)&p_lds[wave][r][j4];
            float p0 = bf16bits_to_f(pp.x & 0xffffu);
            float p1 = __uint_as_float(pp.x & 0xffff0000u);
            float p2 = bf16bits_to_f(pp.y & 0xffffu);
            float p3 = __uint_as_float(pp.y & 0xffff0000u);
            acc[r] += p0 * v0 + p1 * v1 + p2 * v2 + p3 * v3;
        }
    }
    float v196 = bf16bits_to_f((uint)vb[196 * 64]);
#pragma unroll
    for (int r = 0; r < RW; ++r) {
        int i = i0 + r;
        if (i < S_) {
            float p196 = bf16bits_to_f((uint)p_lds[wave][r][196]);
            float a = acc[r] + p196 * v196;
            o[((size_t)(bb * S_) + i) * E_ + hh * DH_ + lane] = __float2bfloat16(a);
        }
    }
}

// ---------------- head with fused final LN (64 n per block, 4-way e-split) ----------------
__global__ __launch_bounds__(256) void head_ln_kernel(const float* __restrict__ h,
                                                      const float* __restrict__ lw,
                                                      const float* __restrict__ lb,
                                                      const float* __restrict__ hw,
                                                      const float* __restrict__ hb,
                                                      float* __restrict__ out) {
    int b = blockIdx.y;
    int tid = threadIdx.x;
    const float* xr0 = h + (size_t)(b * S_) * E_;
    float v0 = xr0[tid], v1 = xr0[tid + 256], v2 = xr0[tid + 512];
    float s  = v0 + v1 + v2;
    float sq = v0 * v0 + v1 * v1 + v2 * v2;
#pragma unroll
    for (int m = 1; m < 64; m <<= 1) {
        s  += __shfl_xor(s, m, 64);
        sq += __shfl_xor(sq, m, 64);
    }
    __shared__ float ss[4], sqs[4];
    __shared__ float xr[E_];
    __shared__ float partial[4][64];
    int wave = tid >> 6, lane = tid & 63;
    if (lane == 0) { ss[wave] = s; sqs[wave] = sq; }
    __syncthreads();
    s  = ss[0] + ss[1] + ss[2] + ss[3];
    sq = sqs[0] + sqs[1] + sqs[2] + sqs[3];
    float mu   = s * (1.0f / 768.0f);
    float var  = sq * (1.0f / 768.0f) - mu * mu;
    float rstd = rsqrtf(var + 1e-5f);
    xr[tid]       = (v0 - mu) * rstd * lw[tid]       + lb[tid];
    xr[tid + 256] = (v1 - mu) * rstd * lw[tid + 256] + lb[tid + 256];
    xr[tid + 512] = (v2 - mu) * rstd * lw[tid + 512] + lb[tid + 512];
    __syncthreads();
    int nl = tid & 63, eq = tid >> 6;
    int n = blockIdx.x * 64 + nl;
    float acc = 0.f;
    if (n < OUT_) {
        int e0 = eq * 192;
        for (int e = e0; e < e0 + 192; ++e) acc += xr[e] * hw[(size_t)e * OUT_ + n];
    }
    partial[eq][nl] = acc;
    __syncthreads();
    if (eq == 0 && n < OUT_)
        out[(size_t)b * OUT_ + n] = partial[0][nl] + partial[1][nl] + partial[2][nl] + partial[3][nl] + hb[n];
}

extern "C" void kernel_launch(void* const* d_in, const int* in_sizes, int n_in,
                              void* d_out, int out_size, void* d_ws, size_t ws_size,
                              hipStream_t stream) {
    const float* x        = (const float*)d_in[0];
    const float* conv_w   = (const float*)d_in[1];
    const float* conv_b   = (const float*)d_in[2];
    const float* pos_e    = (const float*)d_in[3];
    const float* cls_t    = (const float*)d_in[4];
    const float* ln1_w    = (const float*)d_in[5];
    const float* ln1_b    = (const float*)d_in[6];
    const float* attn_w   = (const float*)d_in[7];
    const float* attn_b   = (const float*)d_in[8];
    const float* proj_w   = (const float*)d_in[9];
    const float* proj_b   = (const float*)d_in[10];
    const float* ln2_w    = (const float*)d_in[11];
    const float* ln2_b    = (const float*)d_in[12];
    const float* fc1_w    = (const float*)d_in[13];
    const float* fc1_b    = (const float*)d_in[14];
    const float* fc2_w    = (const float*)d_in[15];
    const float* fc2_b    = (const float*)d_in[16];
    const float* lnf_w    = (const float*)d_in[17];
    const float* lnf_b    = (const float*)d_in[18];
    const float* head_w   = (const float*)d_in[19];
    const float* head_b   = (const float*)d_in[20];
    float* out = (float*)d_out;

    // workspace layout (16B-aligned regions)
    float* h      = (float*)d_ws;                                 // 605184 f
    float* part0q = h + (size_t)ROWS_ * E_;                       // 1815552 f (patch tmp / QKV part0)
    __hip_bfloat16* lnb = (__hip_bfloat16*)(part0q + (size_t)ROWS_ * 3 * E_);
    __hip_bfloat16* ao  = lnb + (size_t)ROWS_ * E_;               // part1 region begin
    __hip_bfloat16* hid = ao + (size_t)ROWS_ * E_;
    __hip_bfloat16* aim = hid + (size_t)ROWS_ * DFF_;
    __hip_bfloat16* pad = aim + (size_t)784 * E_;                 // 4096 bf16 pad
    __hip_bfloat16* wt  = pad + 4096;                             // 14745600 bf16
    ushort* ktg = (ushort*)(wt + (size_t)14745600);               // 48*64*256
    float* ksg  = (float*)(ktg + (size_t)48 * 64 * KT_PP);        // 48*256 f
    float* qsg  = ksg + (size_t)48 * KT_PP;                       // 48*200 f
    ushort* qg  = (ushort*)(qsg + (size_t)48 * 200);              // 48*12608
    ushort* vg  = qg + (size_t)48 * QH_P;                         // 48*12608
    float* part = (float*)(vg + (size_t)48 * QH_P);               // 2*788*768 f (fc2)
    float* qscr = (float*)ao;                                     // QKV part1 (ao..pad = 7.26 MB)

    // ---- prologue: merged prep, patch gemm, fused embed+LN1(l=0) ----
    prep_all_kernel<<<18480, 256, 0, stream>>>(x, aim, attn_w, proj_w, fc1_w, fc2_w, conv_w, wt);
    {
        dim3 grid(E_ / 64, (784 + 63) / 64);
        gemm_mfma_kernel<<<grid, 256, 0, stream>>>(aim, wt + WT_CONV, conv_b, nullptr, part0q, nullptr,
                                                   nullptr, nullptr, 784, E_, E_, 0, 1);
    }
    embed_ln_kernel<<<ROWS_, 256, 0, stream>>>(part0q, pos_e, cls_t, ln1_w, ln1_b, h, lnb);

    for (int l = 0; l < LL_; ++l) {
        const __hip_bfloat16* wl = wt + WT_LBASE + (size_t)l * WT_LSTRIDE;
        // QKV split-K=2 raw partials (part0 = part0q, part1 = qscr)
        {
            dim3 grid((3 * E_) / 64, (ROWS_ + 63) / 64, 2);
            gemm_mfma_kernel<<<grid, 256, 0, stream>>>(lnb, wl + WT_QKV, nullptr, nullptr,
                                                       nullptr, nullptr, part0q, qscr,
                                                       ROWS_, 3 * E_, E_, 0, 2);
        }
        // attention (prep absorbs reduce+bias; emits compact bf16 q/k/v + sums)
        {
            attn_prep_kernel<<<dim3(NH_, B_, 4), 256, 0, stream>>>(
                part0q, qscr, attn_b + (size_t)l * 3 * E_, ktg, ksg, qg, vg, qsg);
            dim3 grid((S_ + CHUNK - 1) / CHUNK, NH_, B_);   // 13 x 12 x 4
            tversky_attn_kernel<<<grid, 256, 0, stream>>>(qg, ktg, ksg, vg, qsg, ao);
        }
        // proj + residual into h
        {
            dim3 grid(E_ / 64, (ROWS_ + 63) / 64);
            gemm_mfma_kernel<<<grid, 256, 0, stream>>>(ao, wl + WT_PROJ, proj_b + (size_t)l * E_,
                                                       h, h, nullptr, nullptr, nullptr,
                                                       ROWS_, E_, E_, 0, 1);
        }
        layernorm_kernel<<<ROWS_, 256, 0, stream>>>(h, ln2_w + l * E_, ln2_b + l * E_, lnb);
        // fc1 + gelu
        {
            dim3 grid(DFF_ / 64, (ROWS_ + 63) / 64);
            gemm_mfma_kernel<<<grid, 256, 0, stream>>>(lnb, wl + WT_FC1, fc1_b + (size_t)l * DFF_,
                                                       nullptr, nullptr, hid, nullptr, nullptr,
                                                       ROWS_, DFF_, E_, 1, 1);
        }
        // fc2 split-K=2 -> part; reduce + bias + residual -> h
        {
            dim3 grid(E_ / 64, (ROWS_ + 63) / 64, 2);
            gemm_mfma_kernel<<<grid, 256, 0, stream>>>(hid, wl + WT_FC2, nullptr, nullptr, nullptr,
                                                       nullptr, part, part + (size_t)ROWS_ * E_,
                                                       ROWS_, E_, DFF_, 0, 2);
            splitk_reduce_kernel<<<(ROWS_ * E_ + 255) / 256, 256, 0, stream>>>(
                part, part + (size_t)ROWS_ * E_, fc2_b + (size_t)l * E_, h, h, ROWS_, E_);
        }
        if (l == 0)
            layernorm_kernel<<<ROWS_, 256, 0, stream>>>(h, ln1_w + E_, ln1_b + E_, lnb);
    }

    {
        dim3 grid((OUT_ + 63) / 64, B_);
        head_ln_kernel<<<grid, 256, 0, stream>>>(h, lnf_w, lnf_b, head_w, head_b, out);
    }
}

// Round 11
// 389.000 us; speedup vs baseline: 1.1011x; 1.1011x over previous
//
#include <hip/hip_runtime.h>
#include <hip/hip_bf16.h>
#include <math.h>

// Shapes
#define B_  4
#define E_  768
#define NH_ 12
#define DH_ 64
#define LL_ 2
#define DFF_ 3072
#define OUT_ 1000
#define S_  197
#define ROWS_ 788          // B_*S_
#define QH_P 12608         // 197*64 per-head q/v pitch

typedef __bf16 bf16x8_t __attribute__((ext_vector_type(8)));
typedef float f32x4_t __attribute__((ext_vector_type(4)));

__device__ __forceinline__ float gelu_f(float x) {
    float x3 = x * x * x;
    return 0.5f * x * (1.0f + tanhf(0.7978845608028654f * (x + 0.044715f * x3)));
}
__device__ __forceinline__ float bf16bits_to_f(uint u) { return __uint_as_float(u << 16); }
__device__ __forceinline__ ushort f_to_bf16bits(float f) {
    __hip_bfloat16 b = __float2bfloat16(f);
    return *(ushort*)&b;
}

// ---------------- merged prologue prep: im2col + all weight transposes + conv cvt ----------------
#define WT_CONV   0
#define WT_LBASE  589824
#define WT_LSTRIDE 7077888
#define WT_QKV    0
#define WT_PROJ   1769472
#define WT_FC1    2359296
#define WT_FC2    4718592
__global__ __launch_bounds__(256) void prep_all_kernel(const float* __restrict__ x,
                                                       __hip_bfloat16* __restrict__ aim,
                                                       const float* __restrict__ attn_w,
                                                       const float* __restrict__ proj_w,
                                                       const float* __restrict__ fc1_w,
                                                       const float* __restrict__ fc2_w,
                                                       const float* __restrict__ conv_w,
                                                       __hip_bfloat16* __restrict__ wt) {
    int bid = blockIdx.x;
    if (bid < 2352) {                       // im2col
        int id = bid * 256 + threadIdx.x;
        int row = id / 768, k = id - row * 768;
        int b = row / 196, pr = row - b * 196;
        int hp = pr / 14, wp = pr - hp * 14;
        int c = k >> 8, rem = k & 255, p = rem >> 4, q = rem & 15;
        aim[id] = __float2bfloat16(x[(((size_t)(b * 3 + c) * 224) + hp * 16 + p) * 224 + wp * 16 + q]);
        return;
    }
    int id = bid - 2352;
    if (id >= 13824) {                      // conv cvt (already [N,K])
        int off = (id - 13824) * 256 + threadIdx.x;
        wt[WT_CONV + off] = __float2bfloat16(conv_w[off]);
        return;
    }
    int l = id / 6912, r = id - l * 6912;
    const float* src;
    __hip_bfloat16* dst;
    int K, N, tile;
    size_t lbase = WT_LBASE + (size_t)l * WT_LSTRIDE;
    if (r < 1728)      { src = attn_w + (size_t)l * E_ * 3 * E_; dst = wt + lbase + WT_QKV;  K = E_;   N = 3 * E_; tile = r; }
    else if (r < 2304) { src = proj_w + (size_t)l * E_ * E_;     dst = wt + lbase + WT_PROJ; K = E_;   N = E_;     tile = r - 1728; }
    else if (r < 4608) { src = fc1_w + (size_t)l * E_ * DFF_;    dst = wt + lbase + WT_FC1;  K = E_;   N = DFF_;   tile = r - 2304; }
    else               { src = fc2_w + (size_t)l * DFF_ * E_;    dst = wt + lbase + WT_FC2;  K = DFF_; N = E_;     tile = r - 4608; }
    int ntn = N / 32;
    int kb = (tile / ntn) * 32, nb = (tile % ntn) * 32;
    __shared__ __hip_bfloat16 t[32][33];
    int tx = threadIdx.x & 31, ty = threadIdx.x >> 5;
#pragma unroll
    for (int rr = 0; rr < 32; rr += 8)
        t[ty + rr][tx] = __float2bfloat16(src[(size_t)(kb + ty + rr) * N + nb + tx]);
    __syncthreads();
#pragma unroll
    for (int rr = 0; rr < 32; rr += 8)
        dst[(size_t)(nb + ty + rr) * K + kb + tx] = t[tx][ty + rr];
}

// ---------------- MFMA GEMM: LDS dbuf, 1 barrier/iter, prefetch depth 2, split-K ----------------
#define BK 64
#define AP 72
__global__ __launch_bounds__(256) void gemm_mfma_kernel(const __hip_bfloat16* __restrict__ A,
                                                        const __hip_bfloat16* __restrict__ WT,
                                                        const float* __restrict__ bias,
                                                        const float* __restrict__ res,
                                                        float* __restrict__ Cf,
                                                        __hip_bfloat16* __restrict__ Cb,
                                                        float* __restrict__ part0,
                                                        float* __restrict__ part1,
                                                        int M, int N, int K, int act, int KS) {
    __shared__ __align__(16) ushort Asb[2][64 * AP];
    __shared__ __align__(16) ushort Bsb[2][64 * AP];
    const int tid = threadIdx.x;
    const int wave = tid >> 6, lane = tid & 63;
    const int quad = lane >> 4, l15 = lane & 15;
    const int wm = wave >> 1, wn = wave & 1;
    const int m0 = blockIdx.y * 64, n0 = blockIdx.x * 64;

    const int Kc   = K / KS;
    const int kbeg = blockIdx.z * Kc;
    const int n_it = Kc / BK;

    f32x4_t acc[2][2] = {};

    const int c0r = tid >> 3,         c0o = (tid & 7) * 8;
    const int c1r = (tid + 256) >> 3, c1o = c0o;

    uint4 pa0, pa1, pb0, pb1;
    auto load_tile = [&](int kk) {
        pa0 = make_uint4(0, 0, 0, 0);
        pa1 = pa0;
        int gm = m0 + c0r;
        if (gm < M) pa0 = *(const uint4*)&A[(size_t)gm * K + kk + c0o];
        gm = m0 + c1r;
        if (gm < M) pa1 = *(const uint4*)&A[(size_t)gm * K + kk + c1o];
        pb0 = *(const uint4*)&WT[(size_t)(n0 + c0r) * K + kk + c0o];
        pb1 = *(const uint4*)&WT[(size_t)(n0 + c1r) * K + kk + c1o];
    };
    auto store_tile = [&](int buf) {
        *(uint4*)&Asb[buf][c0r * AP + c0o] = pa0;
        *(uint4*)&Asb[buf][c1r * AP + c1o] = pa1;
        *(uint4*)&Bsb[buf][c0r * AP + c0o] = pb0;
        *(uint4*)&Bsb[buf][c1r * AP + c1o] = pb1;
    };

    load_tile(kbeg);
    store_tile(0);
    if (n_it > 1) load_tile(kbeg + BK);
    __syncthreads();

    for (int it = 0; it < n_it; ++it) {
        const int cur = it & 1, nxt = cur ^ 1;
        if (it + 1 < n_it) {
            store_tile(nxt);
            if (it + 2 < n_it) load_tile(kbeg + (it + 2) * BK);
        }
        const ushort* As = Asb[cur];
        const ushort* Bs = Bsb[cur];
#pragma unroll
        for (int ks = 0; ks < BK; ks += 32) {
            bf16x8_t a0 = *(const bf16x8_t*)&As[(32 * wm + l15) * AP + ks + 8 * quad];
            bf16x8_t a1 = *(const bf16x8_t*)&As[(32 * wm + 16 + l15) * AP + ks + 8 * quad];
            bf16x8_t b0 = *(const bf16x8_t*)&Bs[(32 * wn + l15) * AP + ks + 8 * quad];
            bf16x8_t b1 = *(const bf16x8_t*)&Bs[(32 * wn + 16 + l15) * AP + ks + 8 * quad];
            acc[0][0] = __builtin_amdgcn_mfma_f32_16x16x32_bf16(a0, b0, acc[0][0], 0, 0, 0);
            acc[0][1] = __builtin_amdgcn_mfma_f32_16x16x32_bf16(a0, b1, acc[0][1], 0, 0, 0);
            acc[1][0] = __builtin_amdgcn_mfma_f32_16x16x32_bf16(a1, b0, acc[1][0], 0, 0, 0);
            acc[1][1] = __builtin_amdgcn_mfma_f32_16x16x32_bf16(a1, b1, acc[1][1], 0, 0, 0);
        }
        __syncthreads();
    }

    if (part0) {
        float* P = blockIdx.z ? part1 : part0;
#pragma unroll
        for (int mi = 0; mi < 2; ++mi)
#pragma unroll
            for (int ni = 0; ni < 2; ++ni) {
                int gn = n0 + 32 * wn + 16 * ni + l15;
#pragma unroll
                for (int r = 0; r < 4; ++r) {
                    int gm = m0 + 32 * wm + 16 * mi + quad * 4 + r;
                    if (gm < M) P[(size_t)gm * N + gn] = acc[mi][ni][r];
                }
            }
        return;
    }

#pragma unroll
    for (int mi = 0; mi < 2; ++mi)
#pragma unroll
        for (int ni = 0; ni < 2; ++ni) {
            int gn = n0 + 32 * wn + 16 * ni + l15;
#pragma unroll
            for (int r = 0; r < 4; ++r) {
                int gm = m0 + 32 * wm + 16 * mi + quad * 4 + r;
                if (gm < M) {
                    float v = acc[mi][ni][r] + bias[gn];
                    if (act == 1) v = gelu_f(v);
                    if (res) v += res[(size_t)gm * N + gn];
                    if (Cf) Cf[(size_t)gm * N + gn] = v;
                    else    Cb[(size_t)gm * N + gn] = __float2bfloat16(v);
                }
            }
        }
}

// ---------------- split-K(2) reduce (fp32 out) ----------------
__global__ __launch_bounds__(256) void splitk_reduce_kernel(const float* __restrict__ p0,
                                                            const float* __restrict__ p1,
                                                            const float* __restrict__ bias,
                                                            const float* __restrict__ res,
                                                            float* __restrict__ Cf,
                                                            int M, int N) {
    int i = blockIdx.x * 256 + threadIdx.x;
    if (i >= M * N) return;
    int n = i % N;
    float v = bias[n] + p0[i] + p1[i];
    if (res) v += res[i];
    Cf[i] = v;
}

// ---------------- embed (split-K patch parts + conv_b + pe) + cls + LN1(l=0) fused ----------------
__global__ __launch_bounds__(256) void embed_ln_kernel(const float* __restrict__ p0,
                                                       const float* __restrict__ p1,
                                                       const float* __restrict__ cb,
                                                       const float* __restrict__ pe,
                                                       const float* __restrict__ ct,
                                                       const float* __restrict__ lw,
                                                       const float* __restrict__ lb,
                                                       float* __restrict__ h,
                                                       __hip_bfloat16* __restrict__ y) {
    int row = blockIdx.x, tid = threadIdx.x;
    int b = row / S_, s = row - b * S_;
    float v[3];
#pragma unroll
    for (int c = 0; c < 3; ++c) {
        int e = tid + c * 256;
        float t;
        if (s == 0) t = ct[e];
        else {
            int pr = s - 1;
            size_t gi = (size_t)(b * 196 + pr) * E_ + e;
            t = p0[gi] + p1[gi] + cb[e] + pe[(size_t)pr * E_ + e];
        }
        h[(size_t)row * E_ + e] = t;
        v[c] = t;
    }
    float sm  = v[0] + v[1] + v[2];
    float sq = v[0] * v[0] + v[1] * v[1] + v[2] * v[2];
#pragma unroll
    for (int m = 1; m < 64; m <<= 1) {
        sm += __shfl_xor(sm, m, 64);
        sq += __shfl_xor(sq, m, 64);
    }
    __shared__ float ss[4], sqs[4];
    int wave = tid >> 6, lane = tid & 63;
    if (lane == 0) { ss[wave] = sm; sqs[wave] = sq; }
    __syncthreads();
    sm = ss[0] + ss[1] + ss[2] + ss[3];
    sq = sqs[0] + sqs[1] + sqs[2] + sqs[3];
    float mu   = sm * (1.0f / 768.0f);
    float var  = sq * (1.0f / 768.0f) - mu * mu;
    float rstd = rsqrtf(var + 1e-5f);
    __hip_bfloat16* yr = y + (size_t)row * E_;
#pragma unroll
    for (int c = 0; c < 3; ++c) {
        int e = tid + c * 256;
        yr[e] = __float2bfloat16((v[c] - mu) * rstd * lw[e] + lb[e]);
    }
}

// ---------------- LayerNorm (fp32 in, bf16 out) ----------------
__global__ __launch_bounds__(256) void layernorm_kernel(const float* __restrict__ x,
                                                        const float* __restrict__ w,
                                                        const float* __restrict__ b,
                                                        __hip_bfloat16* __restrict__ y) {
    int row = blockIdx.x;
    const float* xr = x + (size_t)row * E_;
    int tid = threadIdx.x;
    float v0 = xr[tid], v1 = xr[tid + 256], v2 = xr[tid + 512];
    float s  = v0 + v1 + v2;
    float sq = v0 * v0 + v1 * v1 + v2 * v2;
#pragma unroll
    for (int m = 1; m < 64; m <<= 1) {
        s  += __shfl_xor(s, m, 64);
        sq += __shfl_xor(sq, m, 64);
    }
    __shared__ float ss[4], sqs[4];
    int wave = tid >> 6, lane = tid & 63;
    if (lane == 0) { ss[wave] = s; sqs[wave] = sq; }
    __syncthreads();
    s  = ss[0] + ss[1] + ss[2] + ss[3];
    sq = sqs[0] + sqs[1] + sqs[2] + sqs[3];
    float mu   = s * (1.0f / 768.0f);
    float var  = sq * (1.0f / 768.0f) - mu * mu;
    float rstd = rsqrtf(var + 1e-5f);
    __hip_bfloat16* yr = y + (size_t)row * E_;
    yr[tid]       = __float2bfloat16((v0 - mu) * rstd * w[tid]       + b[tid]);
    yr[tid + 256] = __float2bfloat16((v1 - mu) * rstd * w[tid + 256] + b[tid + 256]);
    yr[tid + 512] = __float2bfloat16((v2 - mu) * rstd * w[tid + 512] + b[tid + 512]);
}

// ---------------- attention prep (absorbs QKV split-K reduce + bias), 8 z-slices ----------------
// z=0..3: K j-chunks (52) -> ktg bf16 [head][d*256+j] + ksg; z=4,5: V halves -> vg [head][j*64+d];
// z=6,7: Q halves -> qg [head][i*64+d] (relu) + qsg row sums.
#define KT_PP 256
#define PJL 52
__global__ __launch_bounds__(256) void attn_prep_kernel(const float* __restrict__ p0,
                                                        const float* __restrict__ p1,
                                                        const float* __restrict__ ab,
                                                        ushort* __restrict__ ktg,
                                                        float* __restrict__ ksg,
                                                        ushort* __restrict__ qg,
                                                        ushort* __restrict__ vg,
                                                        float* __restrict__ qsg) {
    const int tid = threadIdx.x;
    const int lane = tid & 63;
    const int hh = blockIdx.x, bb = blockIdx.y, zc = blockIdx.z;
    const int head = bb * NH_ + hh;

    if (zc <= 3) {                      // K chunk -> kT transpose + ks
        __shared__ float kT[64][PJL + 1];
        const int j0 = zc * PJL;
        float* ksrow = ksg + (size_t)head * KT_PP;
        for (int c = 0; c < 13; ++c) {
            int idx = c * 256 + tid;
            int jj = idx >> 6, d = idx & 63;
            int j = j0 + jj;
            float val = 0.f;
            if (j < S_) {
                size_t g = ((size_t)(bb * S_ + j)) * (3 * E_) + E_ + hh * DH_ + d;
                val = fmaxf(p0[g] + p1[g] + ab[E_ + hh * DH_ + d], 0.f);
            }
            kT[d][jj] = val;
            float s = val;
#pragma unroll
            for (int m = 1; m < 64; m <<= 1) s += __shfl_xor(s, m, 64);
            if (j < S_ && lane == 0) ksrow[j] = s;
        }
        if (zc == 3) {
            int jp = 3 * PJL + tid;
            if (jp >= S_ && jp < KT_PP) ksrow[jp] = 0.f;   // pad 197..255
        }
        __syncthreads();
        ushort* orow = ktg + (size_t)head * 64 * KT_PP + j0;
        for (int idx = tid; idx < 64 * PJL; idx += 256) {
            int d = idx / PJL, jj = idx - d * PJL;
            orow[(size_t)d * KT_PP + jj] = f_to_bf16bits(kT[d][jj]);
        }
    } else if (zc <= 5) {               // V half
        const int jb = (zc - 4) * 100;
        for (int c = 0; c < 25; ++c) {
            int idx = c * 256 + tid;
            int j = jb + (idx >> 6), d = idx & 63;
            if (j < S_) {
                size_t g = ((size_t)(bb * S_ + j)) * (3 * E_) + 2 * E_ + hh * DH_ + d;
                vg[(size_t)head * QH_P + j * 64 + d] = f_to_bf16bits(p0[g] + p1[g] + ab[2 * E_ + hh * DH_ + d]);
            }
        }
    } else {                            // Q half: relu + row sums
        const int wv = tid >> 6;
        const int ib = (zc - 6) * 100;
        for (int c = 0; c < 25; ++c) {
            int i = ib + c * 4 + wv;
            float val = 0.f;
            if (i < S_) {
                size_t g = ((size_t)(bb * S_ + i)) * (3 * E_) + hh * DH_ + lane;
                val = fmaxf(p0[g] + p1[g] + ab[hh * DH_ + lane], 0.f);
                qg[(size_t)head * QH_P + i * 64 + lane] = f_to_bf16bits(val);
            }
            float s = val;
#pragma unroll
            for (int m = 1; m < 64; m <<= 1) s += __shfl_xor(s, m, 64);
            if (i < S_ && lane == 0) qsg[(size_t)head * 200 + i] = s;
        }
    }
}

// ---------------- Tversky attention: j-split partials, kT bf16 LDS, j-pair lanes, RW=4 ----------------
// score = (qs+ks-l1)/(qs+ks+2eps) in [~0,1]; no-max softmax; emit num (fp32), den per j-half.
#define RW 4
#define CHUNK (4 * RW)     // 16 q-rows per block
#define KT_HP 128          // local kT pitch (ushorts)
__global__ __launch_bounds__(256) void tversky_attn_kernel(const ushort* __restrict__ qg,
                                                           const ushort* __restrict__ ktg,
                                                           const float* __restrict__ ksg,
                                                           const ushort* __restrict__ vg,
                                                           const float* __restrict__ qsg,
                                                           float* __restrict__ numg,
                                                           float* __restrict__ deng) {
    __shared__ __align__(16) ushort kT[64 * KT_HP];      // 16384 B
    __shared__ __align__(16) float ks_l[KT_PP];          // 1024 B
    __shared__ __align__(16) float q_lds[4][RW][64];     // 4096 B
    __shared__ __align__(16) ushort p_lds[4][RW][104];   // 3328 B

    const int tid  = threadIdx.x;
    const int wave = tid >> 6;
    const int lane = tid & 63;
    const int bx = blockIdx.x;          // 0..25
    const int ch = bx >> 1, jh = bx & 1;
    const int hh = blockIdx.y, bb = blockIdx.z;
    const int head = bb * NH_ + hh;
    const int j0 = jh * 104;

    // stage kT half (64 rows x 16 uint4; cols beyond 207 are deterministic pad) + ks
    {
        const ushort* srcb = ktg + (size_t)head * 64 * KT_PP + j0;
        for (int c = 0; c < 4; ++c) {
            int idx = c * 256 + tid;          // 0..1023
            int d = idx >> 4, cu = idx & 15;
            *(uint4*)&kT[d * KT_HP + cu * 8] = *(const uint4*)&srcb[(size_t)d * KT_PP + cu * 8];
        }
        ks_l[tid] = ksg[(size_t)head * KT_PP + tid];
    }
    __syncthreads();

    const int i0 = ch * CHUNK + wave * RW;
    if (i0 >= S_) return;   // after last barrier: safe

    float qs[RW];
#pragma unroll
    for (int r = 0; r < RW; ++r) {
        int i = i0 + r;
        float qp = 0.f, qsv = 0.f;
        if (i < S_) {
            qp  = bf16bits_to_f((uint)qg[(size_t)head * QH_P + i * 64 + lane]);
            qsv = qsg[(size_t)head * 200 + i];
        }
        qs[r] = qsv;
        q_lds[wave][r][lane] = qp;
    }

    // lane covers j-pair {j0+2l, j0+2l+1}
    const bool b0 = lane <= (jh ? 46 : 51);
    const bool b1 = lane <= (jh ? 45 : 51);
    const int koff = 2 * lane;          // <= 126 < KT_HP

    float l[2][RW] = {};
#pragma unroll 4
    for (int d4 = 0; d4 < 16; ++d4) {
        float4 qv[RW];
#pragma unroll
        for (int r = 0; r < RW; ++r) qv[r] = *(const float4*)&q_lds[wave][r][d4 * 4];
#pragma unroll
        for (int dd = 0; dd < 4; ++dd) {
            int d = d4 * 4 + dd;
            uint kp = *(const uint*)&kT[d * KT_HP + koff];
            float k0 = bf16bits_to_f(kp & 0xffffu);
            float k1 = __uint_as_float(kp & 0xffff0000u);
#pragma unroll
            for (int r = 0; r < RW; ++r) {
                float q = (dd == 0) ? qv[r].x : (dd == 1) ? qv[r].y : (dd == 2) ? qv[r].z : qv[r].w;
                l[0][r] += fabsf(q - k0);
                l[1][r] += fabsf(q - k1);
            }
        }
    }

    float2 ks2 = *(const float2*)&ks_l[j0 + 2 * lane];

#pragma unroll
    for (int r = 0; r < RW; ++r) {
        float s0 = qs[r] + ks2.x, s1 = qs[r] + ks2.y;
        float e0 = b0 ? expf((s0 - l[0][r]) / (s0 + 2e-8f)) : 0.f;
        float e1 = b1 ? expf((s1 - l[1][r]) / (s1 + 2e-8f)) : 0.f;
        float sum = e0 + e1;
#pragma unroll
        for (int m = 1; m < 64; m <<= 1) sum += __shfl_xor(sum, m, 64);
        int i = i0 + r;
        if (lane == 0 && i < S_) deng[(size_t)(jh * 48 + head) * 200 + i] = sum;
        if (lane <= 51) {    // lanes 0..51 x 2 = p[0..103] fully written (zeros where invalid)
            uint w = (uint)f_to_bf16bits(e0) | ((uint)f_to_bf16bits(e1) << 16);
            *(uint*)&p_lds[wave][r][2 * lane] = w;
        }
    }
    // p_lds written & read by same wave only: no barrier needed

    const ushort* vb = vg + (size_t)head * QH_P + lane;
    float acc[RW] = {};
#pragma unroll 2
    for (int jj = 0; jj < 104; jj += 4) {           // j up to 207: vg pad region (finite) x p=0
        int j = j0 + jj;
        float v0 = bf16bits_to_f((uint)vb[(j + 0) * 64]);
        float v1 = bf16bits_to_f((uint)vb[(j + 1) * 64]);
        float v2 = bf16bits_to_f((uint)vb[(j + 2) * 64]);
        float v3 = bf16bits_to_f((uint)vb[(j + 3) * 64]);
#pragma unroll
        for (int r = 0; r < RW; ++r) {
            uint2 pp = *(const uint2*)&p_lds[wave][r][jj];
            float p0 = bf16bits_to_f(pp.x & 0xffffu);
            float p1 = __uint_as_float(pp.x & 0xffff0000u);
            float p2 = bf16bits_to_f(pp.y & 0xffffu);
            float p3 = __uint_as_float(pp.y & 0xffff0000u);
            acc[r] += p0 * v0 + p1 * v1 + p2 * v2 + p3 * v3;
        }
    }
#pragma unroll
    for (int r = 0; r < RW; ++r) {
        int i = i0 + r;
        if (i < S_)
            numg[(size_t)(jh * 48 + head) * QH_P + i * 64 + lane] = acc[r];
    }
}

// ---------------- attention combine: (n0+n1)/(d0+d1) -> ao bf16 ----------------
__global__ __launch_bounds__(256) void attn_combine_kernel(const float* __restrict__ numg,
                                                           const float* __restrict__ deng,
                                                           __hip_bfloat16* __restrict__ ao) {
    int row = blockIdx.x, tid = threadIdx.x;
    int bb = row / S_, i = row - bb * S_;
    __shared__ float dinv[NH_];
    if (tid < NH_) {
        int head = bb * NH_ + tid;
        float d = deng[(size_t)head * 200 + i] + deng[(size_t)(48 + head) * 200 + i];
        dinv[tid] = 1.f / d;
    }
    __syncthreads();
#pragma unroll
    for (int c = 0; c < 3; ++c) {
        int e = tid + c * 256;
        int hd = e >> 6, d = e & 63;
        int head = bb * NH_ + hd;
        float n = numg[(size_t)head * QH_P + i * 64 + d] +
                  numg[(size_t)(48 + head) * QH_P + i * 64 + d];
        ao[(size_t)row * E_ + e] = __float2bfloat16(n * dinv[hd]);
    }
}

// ---------------- head with fused final LN (64 n per block, 4-way e-split) ----------------
__global__ __launch_bounds__(256) void head_ln_kernel(const float* __restrict__ h,
                                                      const float* __restrict__ lw,
                                                      const float* __restrict__ lb,
                                                      const float* __restrict__ hw,
                                                      const float* __restrict__ hb,
                                                      float* __restrict__ out) {
    int b = blockIdx.y;
    int tid = threadIdx.x;
    const float* xr0 = h + (size_t)(b * S_) * E_;
    float v0 = xr0[tid], v1 = xr0[tid + 256], v2 = xr0[tid + 512];
    float s  = v0 + v1 + v2;
    float sq = v0 * v0 + v1 * v1 + v2 * v2;
#pragma unroll
    for (int m = 1; m < 64; m <<= 1) {
        s  += __shfl_xor(s, m, 64);
        sq += __shfl_xor(sq, m, 64);
    }
    __shared__ float ss[4], sqs[4];
    __shared__ float xr[E_];
    __shared__ float partial[4][64];
    int wave = tid >> 6, lane = tid & 63;
    if (lane == 0) { ss[wave] = s; sqs[wave] = sq; }
    __syncthreads();
    s  = ss[0] + ss[1] + ss[2] + ss[3];
    sq = sqs[0] + sqs[1] + sqs[2] + sqs[3];
    float mu   = s * (1.0f / 768.0f);
    float var  = sq * (1.0f / 768.0f) - mu * mu;
    float rstd = rsqrtf(var + 1e-5f);
    xr[tid]       = (v0 - mu) * rstd * lw[tid]       + lb[tid];
    xr[tid + 256] = (v1 - mu) * rstd * lw[tid + 256] + lb[tid + 256];
    xr[tid + 512] = (v2 - mu) * rstd * lw[tid + 512] + lb[tid + 512];
    __syncthreads();
    int nl = tid & 63, eq = tid >> 6;
    int n = blockIdx.x * 64 + nl;
    float acc = 0.f;
    if (n < OUT_) {
        int e0 = eq * 192;
        for (int e = e0; e < e0 + 192; ++e) acc += xr[e] * hw[(size_t)e * OUT_ + n];
    }
    partial[eq][nl] = acc;
    __syncthreads();
    if (eq == 0 && n < OUT_)
        out[(size_t)b * OUT_ + n] = partial[0][nl] + partial[1][nl] + partial[2][nl] + partial[3][nl] + hb[n];
}

extern "C" void kernel_launch(void* const* d_in, const int* in_sizes, int n_in,
                              void* d_out, int out_size, void* d_ws, size_t ws_size,
                              hipStream_t stream) {
    const float* x        = (const float*)d_in[0];
    const float* conv_w   = (const float*)d_in[1];
    const float* conv_b   = (const float*)d_in[2];
    const float* pos_e    = (const float*)d_in[3];
    const float* cls_t    = (const float*)d_in[4];
    const float* ln1_w    = (const float*)d_in[5];
    const float* ln1_b    = (const float*)d_in[6];
    const float* attn_w   = (const float*)d_in[7];
    const float* attn_b   = (const float*)d_in[8];
    const float* proj_w   = (const float*)d_in[9];
    const float* proj_b   = (const float*)d_in[10];
    const float* ln2_w    = (const float*)d_in[11];
    const float* ln2_b    = (const float*)d_in[12];
    const float* fc1_w    = (const float*)d_in[13];
    const float* fc1_b    = (const float*)d_in[14];
    const float* fc2_w    = (const float*)d_in[15];
    const float* fc2_b    = (const float*)d_in[16];
    const float* lnf_w    = (const float*)d_in[17];
    const float* lnf_b    = (const float*)d_in[18];
    const float* head_w   = (const float*)d_in[19];
    const float* head_b   = (const float*)d_in[20];
    float* out = (float*)d_out;

    // workspace layout (16B-aligned regions)
    float* h      = (float*)d_ws;                                 // 605184 f
    float* part0q = h + (size_t)ROWS_ * E_;                       // 1815552 f (QKV/patch part0)
    __hip_bfloat16* lnb = (__hip_bfloat16*)(part0q + (size_t)ROWS_ * 3 * E_);
    __hip_bfloat16* ao  = lnb + (size_t)ROWS_ * E_;               // part1 region begin
    __hip_bfloat16* hid = ao + (size_t)ROWS_ * E_;
    __hip_bfloat16* aim = hid + (size_t)ROWS_ * DFF_;
    __hip_bfloat16* pad = aim + (size_t)784 * E_;                 // 4096 bf16 pad
    __hip_bfloat16* wt  = pad + 4096;                             // 14745600 bf16
    ushort* ktg = (ushort*)(wt + (size_t)14745600);               // 48*64*256
    float* ksg  = (float*)(ktg + (size_t)48 * 64 * KT_PP);        // 48*256 f
    float* qsg  = ksg + (size_t)48 * KT_PP;                       // 48*200 f
    ushort* qg  = (ushort*)(qsg + (size_t)48 * 200);              // 48*12608
    ushort* vg  = qg + (size_t)48 * QH_P;                         // 48*12608 (+1024 pad)
    float* numg = (float*)(vg + (size_t)48 * QH_P + 1024);        // 2*48*12608 f
    float* deng = numg + (size_t)2 * 48 * QH_P;                   // 2*48*200 f
    float* part = deng + (size_t)2 * 48 * 200;                    // 2*788*768 f
    float* qscr = (float*)ao;                                     // QKV part1 (ao..pad = 7.26 MB)

    // ---- prologue: merged prep, patch gemm (split-K=2), fused embed+LN1(l=0) ----
    prep_all_kernel<<<18480, 256, 0, stream>>>(x, aim, attn_w, proj_w, fc1_w, fc2_w, conv_w, wt);
    {
        dim3 grid(E_ / 64, (784 + 63) / 64, 2);
        gemm_mfma_kernel<<<grid, 256, 0, stream>>>(aim, wt + WT_CONV, nullptr, nullptr, nullptr,
                                                   nullptr, part, part + (size_t)ROWS_ * E_,
                                                   784, E_, E_, 0, 2);
    }
    embed_ln_kernel<<<ROWS_, 256, 0, stream>>>(part, part + (size_t)ROWS_ * E_, conv_b,
                                               pos_e, cls_t, ln1_w, ln1_b, h, lnb);

    for (int l = 0; l < LL_; ++l) {
        const __hip_bfloat16* wl = wt + WT_LBASE + (size_t)l * WT_LSTRIDE;
        // QKV split-K=2 raw partials
        {
            dim3 grid((3 * E_) / 64, (ROWS_ + 63) / 64, 2);
            gemm_mfma_kernel<<<grid, 256, 0, stream>>>(lnb, wl + WT_QKV, nullptr, nullptr,
                                                       nullptr, nullptr, part0q, qscr,
                                                       ROWS_, 3 * E_, E_, 0, 2);
        }
        // attention: prep (8 slices) -> j-split main -> combine
        {
            attn_prep_kernel<<<dim3(NH_, B_, 8), 256, 0, stream>>>(
                part0q, qscr, attn_b + (size_t)l * 3 * E_, ktg, ksg, qg, vg, qsg);
            dim3 grid(26, NH_, B_);                        // 26 x 12 x 4 = 1248 blocks
            tversky_attn_kernel<<<grid, 256, 0, stream>>>(qg, ktg, ksg, vg, qsg, numg, deng);
            attn_combine_kernel<<<ROWS_, 256, 0, stream>>>(numg, deng, ao);
        }
        // proj split-K=2 -> part; reduce + bias + residual -> h
        {
            dim3 grid(E_ / 64, (ROWS_ + 63) / 64, 2);
            gemm_mfma_kernel<<<grid, 256, 0, stream>>>(ao, wl + WT_PROJ, nullptr, nullptr, nullptr,
                                                       nullptr, part, part + (size_t)ROWS_ * E_,
                                                       ROWS_, E_, E_, 0, 2);
            splitk_reduce_kernel<<<(ROWS_ * E_ + 255) / 256, 256, 0, stream>>>(
                part, part + (size_t)ROWS_ * E_, proj_b + (size_t)l * E_, h, h, ROWS_, E_);
        }
        layernorm_kernel<<<ROWS_, 256, 0, stream>>>(h, ln2_w + l * E_, ln2_b + l * E_, lnb);
        // fc1 + gelu
        {
            dim3 grid(DFF_ / 64, (ROWS_ + 63) / 64);
            gemm_mfma_kernel<<<grid, 256, 0, stream>>>(lnb, wl + WT_FC1, fc1_b + (size_t)l * DFF_,
                                                       nullptr, nullptr, hid, nullptr, nullptr,
                                                       ROWS_, DFF_, E_, 1, 1);
        }
        // fc2 split-K=2 -> part; reduce + bias + residual -> h
        {
            dim3 grid(E_ / 64, (ROWS_ + 63) / 64, 2);
            gemm_mfma_kernel<<<grid, 256, 0, stream>>>(hid, wl + WT_FC2, nullptr, nullptr, nullptr,
                                                       nullptr, part, part + (size_t)ROWS_ * E_,
                                                       ROWS_, E_, DFF_, 0, 2);
            splitk_reduce_kernel<<<(ROWS_ * E_ + 255) / 256, 256, 0, stream>>>(
                part, part + (size_t)ROWS_ * E_, fc2_b + (size_t)l * E_, h, h, ROWS_, E_);
        }
        if (l == 0)
            layernorm_kernel<<<ROWS_, 256, 0, stream>>>(h, ln1_w + E_, ln1_b + E_, lnb);
    }

    {
        dim3 grid((OUT_ + 63) / 64, B_);
        head_ln_kernel<<<grid, 256, 0, stream>>>(h, lnf_w, lnf_b, head_w, head_b, out);
    }
}